// Round 3
// baseline (648.124 us; speedup 1.0000x reference)
//
#include <hip/hip_runtime.h>
#include <hip/hip_fp16.h>

#define TN 64
#define BN 2048
#define G 8
#define NBLK (BN / G)   // 256 blocks x 512 threads, 1 block/CU, SINGLE round

typedef _Float16 h2v __attribute__((ext_vector_type(2)));
typedef _Float16 half8 __attribute__((ext_vector_type(8)));
typedef float float4v __attribute__((ext_vector_type(4)));

union FU {
    uint4 u;
    half8 h8;
    h2v hv[4];
    __half2 h2[4];
    _Float16 f16[8];
};
union H2U { __half2 h; h2v v; };

#define LAUNDER4(v) asm volatile("" : "+v"((v).x), "+v"((v).y), "+v"((v).z), "+v"((v).w))

__device__ __forceinline__ float fast_sigmoid(float x) {
    return __builtin_amdgcn_rcpf(1.f + __expf(-x));
}
__device__ __forceinline__ float fast_tanhf(float x) {
    return fmaf(2.f, fast_sigmoid(2.f * x), -1.f);
}
__device__ __forceinline__ float fdot2f(__half2 a, __half2 b, float c) {
    H2U ua; ua.h = a; H2U ub; ub.h = b;
    return __builtin_amdgcn_fdot2(ua.v, ub.v, c, false);
}
// packed fp16 tanh, transcendental-light rational (Pade[5/4], d2 tuned 15.047):
// tanh(x) ~= x*(945 + 105 x^2 + x^4) / (945 + 420 x^2 + 15.047 x^4), |x| clamped to 4.
// max math err ~7e-4 (vs exp-path fp16 err ~1e-3); 1 h2rcp (2 trans insts) instead of
// h2exp2+h2rcp (4 trans insts). Clamp via v_pk_max/min_f16 (__builtin_elementwise_*,
// since ROCm's fp16 header has no __hmin2/__hmax2).
__device__ __forceinline__ __half2 tanh2p(__half2 x, __half2 c105, __half2 c945,
                                          __half2 c420, __half2 c15,
                                          h2v p4, h2v n4) {
    H2U ux; ux.h = x;
    H2U uc; uc.v = __builtin_elementwise_min(__builtin_elementwise_max(ux.v, n4), p4);
    __half2 xc = uc.h;
    __half2 x2 = __hmul2(xc, xc);
    __half2 num = __hfma2(__hadd2(x2, c105), x2, c945);
    __half2 den = __hfma2(__hfma2(c15, x2, c420), x2, c945);
    __half2 r = h2rcp(den);
    return __hmul2(xc, __hmul2(num, r));
}

// dc swizzled offset (halves): chunk c of row g at slot (c&16)|((c&15)^g)
__device__ __forceinline__ int dc_off(int g, int e) {
    int c = e >> 3;
    int slot = (c & 16) | ((c & 15) ^ (g & 15));
    return g * 256 + slot * 8 + (e & 7);
}

// ---- HW[b,t,f] = H[b,t,:] @ W1[256:384,:] + b1, fp16 linear [b*T+t][128]
__global__ __launch_bounds__(256) void prep_hw(
    const float* __restrict__ H, const float* __restrict__ W1,
    const float* __restrict__ b1, __half* __restrict__ HWh) {
    __shared__ float sH[16 * 128];
    const int i = threadIdx.x;
    const long r0 = (long)blockIdx.x * 16;
    #pragma unroll
    for (int u = 0; u < 8; ++u) sH[u * 256 + i] = H[r0 * 128 + u * 256 + i];
    __syncthreads();
    const int f = i & 127;
    const int half_ = i >> 7;
    float acc[8];
    float bb = b1[f];
    #pragma unroll
    for (int u = 0; u < 8; ++u) acc[u] = bb;
    #pragma unroll 4
    for (int h = 0; h < 128; ++h) {
        float wv = W1[(256 + h) * 128 + f];
        #pragma unroll
        for (int u = 0; u < 8; ++u)
            acc[u] = fmaf(sH[(half_ + 2 * u) * 128 + h], wv, acc[u]);
    }
    #pragma unroll
    for (int u = 0; u < 8; ++u)
        HWh[(r0 + half_ + 2 * u) * 128 + f] = __float2half(acc[u]);
}

// ---- HhT[b][f][t] = fp16(H[b][t][f])
__global__ __launch_bounds__(256) void prep_ht(
    const float* __restrict__ H, __half* __restrict__ HhT) {
    __shared__ __half sh[64 * 128];
    const int b = blockIdx.x, i = threadIdx.x;
    #pragma unroll
    for (int u = 0; u < 32; ++u) {
        int idx = u * 256 + i;
        sh[idx] = __float2half(H[(long)b * 8192 + idx]);
    }
    __syncthreads();
    const int f = i >> 1, t0 = (i & 1) * 32;
    __half* ob = HhT + (long)b * 8192 + (long)i * 32;
    #pragma unroll
    for (int k = 0; k < 32; ++k) ob[k] = sh[(t0 + k) * 128 + f];
}

// ---- W1m: W1[0:256][:] in MFMA B-frag layout (frag fi = w*8+kt)
__global__ __launch_bounds__(256) void prep_w1m(
    const float* __restrict__ W1, __half* __restrict__ W1m) {
    int tid = blockIdx.x * 256 + threadIdx.x;   // 32768
    int fi = tid >> 9, rem = tid & 511, l = rem >> 3, j = rem & 7;
    int w = fi >> 3, kt = fi & 7;
    int row = kt * 32 + (l >> 4) * 8 + j;
    int col = w * 16 + (l & 15);
    W1m[tid] = __float2half(W1[row * 128 + col]);
}

// ---- WTm: Whh^T in MFMA B-frag layout (frag fi = nt*4+kt)
__global__ __launch_bounds__(256) void prep_wtm(
    const float* __restrict__ Whh, __half* __restrict__ WTm) {
    int tid = blockIdx.x * 256 + threadIdx.x;   // 65536
    int fi = tid >> 9, rem = tid & 511, l = rem >> 3, j = rem & 7;
    int nt = fi >> 2, kt = fi & 3;
    int k = kt * 32 + (l >> 4) * 8 + j;
    int n = nt * 16 + (l & 15);
    WTm[tid] = __float2half(Whh[n * 128 + k]);
}

struct SMem {
    __half ht[G * 128 * 64];   // 131072 B  H^T tile [g][f][t], granule-XOR swizzle
    __half dc[G * 256];        //   4096 B  dc_off swizzle (rows m>=8 overread into sg: harmless)
    float sg[G * 512];         //  16384 B  gates [g][512]
    __half spH[G * 128];       //   2048 B  p fp16 [g][128]
    __half ctxH[G * 128];      //   2048 B  ctx fp16 [g][128]
    __half beta[G * 64];       //   1024 B  fp16 beta [g][64]
    __half w2h[128];           //    256 B
    float sY[G * 64];          //   2048 B
};                             // 158976 B total, 1 block/CU

__global__ __launch_bounds__(512, 2) void decoder_scan(
    const float* __restrict__ Y, const float* __restrict__ W2,
    const float* __restrict__ Wih, const float* __restrict__ bih,
    const float* __restrict__ bhh, const float* __restrict__ fcW,
    const float* __restrict__ fcb, const float* __restrict__ fcfW,
    const float* __restrict__ fcfb,
    const __half* __restrict__ HWh, const __half* __restrict__ HhT,
    const uint4* __restrict__ W1m4, const uint4* __restrict__ WTm4,
    float* __restrict__ out) {

    __shared__ SMem sm;

    const int tid = threadIdx.x;
    const int bbase = blockIdx.x * G;
    const int lane = tid & 63;
    const int wv = tid >> 6;            // wave id == batch-group g
    const int g = wv;

    // ---- init ----
    // HW[g][t=lane][0..127] -> laundered registers (64 VGPR)
    uint4 hwr[16];
    {
        const uint4* src = (const uint4*)(HWh + (((long)(bbase + g) * TN + lane) * 128));
        #pragma unroll
        for (int u = 0; u < 16; ++u) { hwr[u] = src[u]; LAUNDER4(hwr[u]); }
    }
    // H^T tile -> LDS with granule swizzle (granule u of row at u ^ (f&7))
    {
        const uint4* src = (const uint4*)(HhT + (long)bbase * 8192);
        #pragma unroll
        for (int u = 0; u < 16; ++u) {
            int idx = u * 512 + tid;             // granule 0..8191
            int f7 = (idx >> 3) & 7;
            ((uint4*)sm.ht)[(idx & ~7) | ((idx & 7) ^ f7)] = src[idx];
        }
    }
    // W1 B-frags (8 = 32 regs), WhhT B-frags (16 = 64 regs), laundered (AGPR-ok)
    uint4 w1f[8];
    #pragma unroll
    for (int kt = 0; kt < 8; ++kt) {
        w1f[kt] = W1m4[(size_t)(wv * 8 + kt) * 64 + lane];
        LAUNDER4(w1f[kt]);
    }
    uint4 wtf[16];
    #pragma unroll
    for (int q = 0; q < 16; ++q) {
        wtf[q] = WTm4[(size_t)(wv * 16 + q) * 64 + lane];
        LAUNDER4(wtf[q]);
    }
    ((unsigned*)sm.dc)[tid] = 0u;
    ((unsigned*)sm.dc)[512 + tid] = 0u;
    if (tid < 128) sm.w2h[tid] = __float2half(W2[tid]);
    sm.sY[tid] = Y[(long)bbase * TN + tid];
    float c0 = 0.f, c1 = 0.f;
    float wihA[4], wihB[4], bsA[4], bsB[4];
    #pragma unroll
    for (int q = 0; q < 4; ++q) {
        wihA[q] = Wih[q * 128 + lane];
        wihB[q] = Wih[q * 128 + 64 + lane];
        bsA[q] = bih[q * 128 + lane] + bhh[q * 128 + lane];
        bsB[q] = bih[q * 128 + 64 + lane] + bhh[q * 128 + 64 + lane];
    }
    const float fcwa = fcW[lane];
    const float fcwb = fcW[64 + lane];
    const float fcw2 = fcW[128], fcb0 = fcb[0];
    __syncthreads();

    #pragma unroll 1
    for (int s = 0; s < TN; ++s) {
        // ==== region A: p + gates MFMAs (rows = g, 8/16 real) ====
        {
            const int m = lane & 15, q = lane >> 4;
            FU a4[4];
            #pragma unroll
            for (int kt = 0; kt < 4; ++kt) {
                int slot = ((kt * 4 + q) & 15) ^ m;      // d-part chunks
                a4[kt].u = *(const uint4*)&sm.dc[m * 256 + slot * 8];
            }
            float4v pacc = (float4v){0.f, 0.f, 0.f, 0.f};
            float4v gacc[4];
            #pragma unroll
            for (int i = 0; i < 4; ++i) gacc[i] = (float4v){0.f, 0.f, 0.f, 0.f};
            #pragma unroll
            for (int kt = 0; kt < 4; ++kt) {
                FU b; b.u = w1f[kt];
                pacc = __builtin_amdgcn_mfma_f32_16x16x32_f16(a4[kt].h8, b.h8, pacc, 0, 0, 0);
            }
            #pragma unroll
            for (int i = 0; i < 4; ++i) {
                #pragma unroll
                for (int kt = 0; kt < 4; ++kt) {
                    FU b; b.u = wtf[i * 4 + kt];
                    gacc[i] = __builtin_amdgcn_mfma_f32_16x16x32_f16(a4[kt].h8, b.h8, gacc[i], 0, 0, 0);
                }
            }
            #pragma unroll
            for (int kt = 0; kt < 4; ++kt) {
                int slot = 16 | (((kt * 4 + q) & 15) ^ m);   // c-part chunks
                FU a; a.u = *(const uint4*)&sm.dc[m * 256 + slot * 8];
                FU b; b.u = w1f[4 + kt];
                pacc = __builtin_amdgcn_mfma_f32_16x16x32_f16(a.h8, b.h8, pacc, 0, 0, 0);
            }
            if (lane < 32) {
                const int row0 = (lane >> 4) * 4, col = lane & 15;
                #pragma unroll
                for (int r = 0; r < 4; ++r)
                    sm.spH[(row0 + r) * 128 + wv * 16 + col] = __float2half(pacc[r]);
                #pragma unroll
                for (int i = 0; i < 4; ++i) {
                    #pragma unroll
                    for (int r = 0; r < 4; ++r)
                        sm.sg[(row0 + r) * 512 + (wv * 4 + i) * 16 + col] = gacc[i][r];
                }
            }
        }
        __syncthreads();   // b1

        // ==== phase 3: wave-local for own g: e -> softmax -> ctx -> y~ -> LSTM ====
        {
            // ph2: e[g][t=lane] over all 128 feats (spH broadcast within wave)
            const uint4* pH = (const uint4*)&sm.spH[g * 128];
            const __half2* w2b = (const __half2*)sm.w2h;
            const __half2 c105 = __float2half2_rn(105.f);
            const __half2 c945 = __float2half2_rn(945.f);
            const __half2 c420 = __float2half2_rn(420.f);
            const __half2 c15  = __float2half2_rn(15.046875f);
            const h2v p4 = {(_Float16)4.f, (_Float16)4.f};
            const h2v n4 = {(_Float16)-4.f, (_Float16)-4.f};
            float ea0 = 0.f, ea1 = 0.f, ea2 = 0.f, ea3 = 0.f;
            #pragma unroll
            for (int u = 0; u < 16; ++u) {
                FU hw; hw.u = hwr[u];
                FU pp; pp.u = pH[u];
                __half2 th0 = tanh2p(__hadd2(hw.h2[0], pp.h2[0]), c105, c945, c420, c15, p4, n4);
                __half2 th1 = tanh2p(__hadd2(hw.h2[1], pp.h2[1]), c105, c945, c420, c15, p4, n4);
                __half2 th2 = tanh2p(__hadd2(hw.h2[2], pp.h2[2]), c105, c945, c420, c15, p4, n4);
                __half2 th3 = tanh2p(__hadd2(hw.h2[3], pp.h2[3]), c105, c945, c420, c15, p4, n4);
                ea0 = fdot2f(th0, w2b[u * 4 + 0], ea0);
                ea1 = fdot2f(th1, w2b[u * 4 + 1], ea1);
                ea2 = fdot2f(th2, w2b[u * 4 + 2], ea2);
                ea3 = fdot2f(th3, w2b[u * 4 + 3], ea3);
            }
            float e = (ea0 + ea1) + (ea2 + ea3);
            // ph3: softmax (|e| bounded ~10, fp32 safe, no max pass)
            float ex = __expf(e);
            float ssum = ex;
            #pragma unroll
            for (int d = 1; d < 64; d <<= 1) ssum += __shfl_xor(ssum, d, 64);
            sm.beta[g * 64 + lane] = __float2half(ex * __builtin_amdgcn_rcpf(ssum));
            // ph4: ctx for f=lane and f=lane+64 (same-wave LDS readback of beta)
            const uint4* bb = (const uint4*)&sm.beta[g * 64];
            const uint4* htb = (const uint4*)sm.ht;
            const int ba = ((g << 7) | lane) << 3;
            const int sw7 = lane & 7;
            float ca0 = 0.f, ca1 = 0.f, cb0 = 0.f, cb1 = 0.f;
            #pragma unroll
            for (int u = 0; u < 8; ++u) {
                FU bt; bt.u = bb[u];
                FU h0; h0.u = htb[ba + (u ^ sw7)];
                FU h1; h1.u = htb[ba + 512 + (u ^ sw7)];
                ca0 = fdot2f(h0.h2[0], bt.h2[0], ca0);
                ca1 = fdot2f(h0.h2[1], bt.h2[1], ca1);
                ca0 = fdot2f(h0.h2[2], bt.h2[2], ca0);
                ca1 = fdot2f(h0.h2[3], bt.h2[3], ca1);
                cb0 = fdot2f(h1.h2[0], bt.h2[0], cb0);
                cb1 = fdot2f(h1.h2[1], bt.h2[1], cb1);
                cb0 = fdot2f(h1.h2[2], bt.h2[2], cb0);
                cb1 = fdot2f(h1.h2[3], bt.h2[3], cb1);
            }
            float ctxA = ca0 + ca1, ctxB = cb0 + cb1;
            sm.ctxH[g * 128 + lane] = __float2half(ctxA);
            sm.ctxH[g * 128 + 64 + lane] = __float2half(ctxB);
            // ph5: y~ via in-wave reduce (covers all 128 f: own + mirror)
            float v = ctxA * fcwa + ctxB * fcwb;
            #pragma unroll
            for (int d = 1; d < 64; d <<= 1) v += __shfl_xor(v, d, 64);
            float syg = v + fmaf(sm.sY[g * 64 + s], fcw2, fcb0);
            // ph7: LSTM cell for feats lane and lane+64
            float a0A = sm.sg[g * 512 + lane]       + fmaf(syg, wihA[0], bsA[0]);
            float a1A = sm.sg[g * 512 + 128 + lane] + fmaf(syg, wihA[1], bsA[1]);
            float a2A = sm.sg[g * 512 + 256 + lane] + fmaf(syg, wihA[2], bsA[2]);
            float a3A = sm.sg[g * 512 + 384 + lane] + fmaf(syg, wihA[3], bsA[3]);
            float a0B = sm.sg[g * 512 + 64 + lane]  + fmaf(syg, wihB[0], bsB[0]);
            float a1B = sm.sg[g * 512 + 192 + lane] + fmaf(syg, wihB[1], bsB[1]);
            float a2B = sm.sg[g * 512 + 320 + lane] + fmaf(syg, wihB[2], bsB[2]);
            float a3B = sm.sg[g * 512 + 448 + lane] + fmaf(syg, wihB[3], bsB[3]);
            float iA = fast_sigmoid(a0A), fA = fast_sigmoid(a1A);
            float gA = fast_tanhf(a2A),  oA = fast_sigmoid(a3A);
            c0 = fmaf(fA, c0, iA * gA);
            float dA = oA * fast_tanhf(c0);
            float iB = fast_sigmoid(a0B), fB = fast_sigmoid(a1B);
            float gB = fast_tanhf(a2B),  oB = fast_sigmoid(a3B);
            c1 = fmaf(fB, c1, iB * gB);
            float dB = oB * fast_tanhf(c1);
            sm.dc[dc_off(g, lane)] = __float2half(dA);
            sm.dc[dc_off(g, 64 + lane)] = __float2half(dB);
            sm.dc[dc_off(g, 128 + lane)] = __float2half(c0);
            sm.dc[dc_off(g, 192 + lane)] = __float2half(c1);
        }
        __syncthreads();   // b2 (step end)
    }

    // ---- epilogue: all 8 waves, wave-local data ----
    {
        float part = __half2float(sm.dc[dc_off(g, lane)]) * fcfW[lane]
                   + __half2float(sm.dc[dc_off(g, 64 + lane)]) * fcfW[64 + lane]
                   + __half2float(sm.ctxH[g * 128 + lane]) * fcfW[128 + lane]
                   + __half2float(sm.ctxH[g * 128 + 64 + lane]) * fcfW[192 + lane];
        #pragma unroll
        for (int d = 1; d < 64; d <<= 1) part += __shfl_xor(part, d, 64);
        if (lane == 0) out[bbase + g] = part + fcfb[0];
    }
}

extern "C" void kernel_launch(void* const* d_in, const int* in_sizes, int n_in,
                              void* d_out, int out_size, void* d_ws, size_t ws_size,
                              hipStream_t stream) {
    const float* H    = (const float*)d_in[0];
    const float* Y    = (const float*)d_in[1];
    const float* W1   = (const float*)d_in[2];
    const float* b1   = (const float*)d_in[3];
    const float* W2   = (const float*)d_in[4];
    // d_in[5] = attn_b2: softmax-shift-invariant, unused
    const float* Wih  = (const float*)d_in[6];
    const float* Whh  = (const float*)d_in[7];
    const float* bih  = (const float*)d_in[8];
    const float* bhh  = (const float*)d_in[9];
    const float* fcW  = (const float*)d_in[10];
    const float* fcb  = (const float*)d_in[11];
    const float* fcfW = (const float*)d_in[12];
    const float* fcfb = (const float*)d_in[13];

    char* ws = (char*)d_ws;
    __half* HWh = (__half*)ws;                            // 32 MB
    __half* HhT = (__half*)(ws + 33554432);               // 32 MB
    __half* W1m = (__half*)(ws + 2 * 33554432);           // 64 KB
    __half* WTm = (__half*)(ws + 2 * 33554432 + 65536);   // 128 KB
    float* out = (float*)d_out;

    prep_hw<<<BN * TN / 16, 256, 0, stream>>>(H, W1, b1, HWh);
    prep_ht<<<BN, 256, 0, stream>>>(H, HhT);
    prep_w1m<<<128, 256, 0, stream>>>(W1, W1m);
    prep_wtm<<<256, 256, 0, stream>>>(Whh, WTm);
    decoder_scan<<<NBLK, 512, 0, stream>>>(Y, W2, Wih, bih, bhh,
                                           fcW, fcb, fcfW, fcfb,
                                           HWh, HhT, (const uint4*)W1m,
                                           (const uint4*)WTm, out);
}

// Round 4
// 571.550 us; speedup vs baseline: 1.1340x; 1.1340x over previous
//
#include <hip/hip_runtime.h>
#include <hip/hip_fp16.h>

#define TN 64
#define BN 2048
#define G 8
#define NBLK (BN / G)   // 256 blocks x 512 threads, 1 block/CU, SINGLE round

// KK = -2/ln2: pre-scales attention-tanh inputs so e-loop computes
// sigma(2x) = 1/(1 + 2^(KK*x)) with no per-element multiply.
#define KK (-2.88539008f)

typedef _Float16 h2v __attribute__((ext_vector_type(2)));
typedef _Float16 half8 __attribute__((ext_vector_type(8)));
typedef float float4v __attribute__((ext_vector_type(4)));

union FU {
    uint4 u;
    half8 h8;
    h2v hv[4];
    __half2 h2[4];
    _Float16 f16[8];
};
union H2U { __half2 h; h2v v; };

#define LAUNDER4(v) asm volatile("" : "+v"((v).x), "+v"((v).y), "+v"((v).z), "+v"((v).w))

__device__ __forceinline__ float fast_sigmoid(float x) {
    return __builtin_amdgcn_rcpf(1.f + __expf(-x));
}
__device__ __forceinline__ float fast_tanhf(float x) {
    return fmaf(2.f, fast_sigmoid(2.f * x), -1.f);
}
__device__ __forceinline__ float fdot2f(__half2 a, __half2 b, float c) {
    H2U ua; ua.h = a; H2U ub; ub.h = b;
    return __builtin_amdgcn_fdot2(ua.v, ub.v, c, false);
}
// packed fp16 sigmoid(2x) where xs = KK*x is PRE-SCALED (KK folded into HWh/W1m):
// tv = 2^xs = e^{-2x}; r = 1/(1+tv). tanh(x) = 2r-1 is folded into softmax
// shift-invariance (e-loop accumulates w2*r; softmax arg = 2*sum).
__device__ __forceinline__ __half2 sig2(__half2 xs, __half2 one2) {
    __half2 tv = h2exp2(xs);
    return h2rcp(__hadd2(tv, one2));
}

// wave64 sum via DPP (row_shr 1/2/4/8 + row_bcast15/31), result broadcast from
// lane 63. ~80 cyc vs ~250+ for 6 dependent ds_bpermute shuffles.
__device__ __forceinline__ float wave_sum64(float x) {
    union FI { float f; int i; };
    FI a, b; a.f = x;
    b.i = __builtin_amdgcn_update_dpp(0, a.i, 0x111, 0xf, 0xf, true); a.f += b.f;
    b.i = __builtin_amdgcn_update_dpp(0, a.i, 0x112, 0xf, 0xf, true); a.f += b.f;
    b.i = __builtin_amdgcn_update_dpp(0, a.i, 0x114, 0xf, 0xf, true); a.f += b.f;
    b.i = __builtin_amdgcn_update_dpp(0, a.i, 0x118, 0xf, 0xf, true); a.f += b.f;
    b.i = __builtin_amdgcn_update_dpp(0, a.i, 0x142, 0xf, 0xf, true); a.f += b.f;
    b.i = __builtin_amdgcn_update_dpp(0, a.i, 0x143, 0xf, 0xf, true); a.f += b.f;
    FI r; r.i = __builtin_amdgcn_readlane(a.i, 63);
    return r.f;
}

// dc swizzled offset (halves): chunk c of row g at slot (c&16)|((c&15)^g)
__device__ __forceinline__ int dc_off(int g, int e) {
    int c = e >> 3;
    int slot = (c & 16) | ((c & 15) ^ (g & 15));
    return g * 256 + slot * 8 + (e & 7);
}

// ---- HW[b,t,f] = KK * (H[b,t,:] @ W1[256:384,:] + b1), fp16 linear [b*T+t][128]
__global__ __launch_bounds__(256) void prep_hw(
    const float* __restrict__ H, const float* __restrict__ W1,
    const float* __restrict__ b1, __half* __restrict__ HWh) {
    __shared__ float sH[16 * 128];
    const int i = threadIdx.x;
    const long r0 = (long)blockIdx.x * 16;
    #pragma unroll
    for (int u = 0; u < 8; ++u) sH[u * 256 + i] = H[r0 * 128 + u * 256 + i];
    __syncthreads();
    const int f = i & 127;
    const int half_ = i >> 7;
    float acc[8];
    float bb = b1[f];
    #pragma unroll
    for (int u = 0; u < 8; ++u) acc[u] = bb;
    #pragma unroll 4
    for (int h = 0; h < 128; ++h) {
        float wv = W1[(256 + h) * 128 + f];
        #pragma unroll
        for (int u = 0; u < 8; ++u)
            acc[u] = fmaf(sH[(half_ + 2 * u) * 128 + h], wv, acc[u]);
    }
    #pragma unroll
    for (int u = 0; u < 8; ++u)
        HWh[(r0 + half_ + 2 * u) * 128 + f] = __float2half(KK * acc[u]);
}

// ---- HhT[b][f][t] = fp16(H[b][t][f])
__global__ __launch_bounds__(256) void prep_ht(
    const float* __restrict__ H, __half* __restrict__ HhT) {
    __shared__ __half sh[64 * 128];
    const int b = blockIdx.x, i = threadIdx.x;
    #pragma unroll
    for (int u = 0; u < 32; ++u) {
        int idx = u * 256 + i;
        sh[idx] = __float2half(H[(long)b * 8192 + idx]);
    }
    __syncthreads();
    const int f = i >> 1, t0 = (i & 1) * 32;
    __half* ob = HhT + (long)b * 8192 + (long)i * 32;
    #pragma unroll
    for (int k = 0; k < 32; ++k) ob[k] = sh[(t0 + k) * 128 + f];
}

// ---- W1m: KK * W1[0:256][:] in MFMA B-frag layout (frag fi = w*8+kt)
__global__ __launch_bounds__(256) void prep_w1m(
    const float* __restrict__ W1, __half* __restrict__ W1m) {
    int tid = blockIdx.x * 256 + threadIdx.x;   // 32768
    int fi = tid >> 9, rem = tid & 511, l = rem >> 3, j = rem & 7;
    int w = fi >> 3, kt = fi & 7;
    int row = kt * 32 + (l >> 4) * 8 + j;
    int col = w * 16 + (l & 15);
    W1m[tid] = __float2half(KK * W1[row * 128 + col]);
}

// ---- WTm: Whh^T in MFMA B-frag layout (frag fi = nt*4+kt)
__global__ __launch_bounds__(256) void prep_wtm(
    const float* __restrict__ Whh, __half* __restrict__ WTm) {
    int tid = blockIdx.x * 256 + threadIdx.x;   // 65536
    int fi = tid >> 9, rem = tid & 511, l = rem >> 3, j = rem & 7;
    int nt = fi >> 2, kt = fi & 3;
    int k = kt * 32 + (l >> 4) * 8 + j;
    int n = nt * 16 + (l & 15);
    WTm[tid] = __float2half(Whh[n * 128 + k]);
}

struct SMem {
    __half ht[G * 128 * 64];   // 131072 B  H^T tile [g][f][t], granule-XOR swizzle
    __half dc[G * 256];        //   4096 B  dc_off swizzle
    float sg[G * 512];         //  16384 B  gates [g][512]
    __half spH[G * 128];       //   2048 B  p fp16 [g][128] (KK-scaled)
    __half ctxH[G * 128];      //   2048 B  ctx fp16 [g][128]
    __half beta[G * 64];       //   1024 B  fp16 beta [g][64]
    __half w2h[128];           //    256 B
    float sY[G * 64];          //   2048 B
};                             // 158976 B total, 1 block/CU

__global__ __launch_bounds__(512, 2) void decoder_scan(
    const float* __restrict__ Y, const float* __restrict__ W2,
    const float* __restrict__ Wih, const float* __restrict__ bih,
    const float* __restrict__ bhh, const float* __restrict__ fcW,
    const float* __restrict__ fcb, const float* __restrict__ fcfW,
    const float* __restrict__ fcfb,
    const __half* __restrict__ HWh, const __half* __restrict__ HhT,
    const uint4* __restrict__ W1m4, const uint4* __restrict__ WTm4,
    float* __restrict__ out) {

    __shared__ SMem sm;

    const int tid = threadIdx.x;
    const int bbase = blockIdx.x * G;
    const int lane = tid & 63;
    const int wv = tid >> 6;            // wave id == batch-group g
    const int g = wv;

    // ---- init ----
    // HW[g][t=lane][0..127] -> laundered registers (64 VGPR)
    uint4 hwr[16];
    {
        const uint4* src = (const uint4*)(HWh + (((long)(bbase + g) * TN + lane) * 128));
        #pragma unroll
        for (int u = 0; u < 16; ++u) { hwr[u] = src[u]; LAUNDER4(hwr[u]); }
    }
    // H^T tile -> LDS with granule swizzle (granule u of row at u ^ (f&7))
    {
        const uint4* src = (const uint4*)(HhT + (long)bbase * 8192);
        #pragma unroll
        for (int u = 0; u < 16; ++u) {
            int idx = u * 512 + tid;             // granule 0..8191
            int f7 = (idx >> 3) & 7;
            ((uint4*)sm.ht)[(idx & ~7) | ((idx & 7) ^ f7)] = src[idx];
        }
    }
    // W1 B-frags (8 = 32 regs), WhhT B-frags (16 = 64 regs), laundered (AGPR-ok)
    uint4 w1f[8];
    #pragma unroll
    for (int kt = 0; kt < 8; ++kt) {
        w1f[kt] = W1m4[(size_t)(wv * 8 + kt) * 64 + lane];
        LAUNDER4(w1f[kt]);
    }
    uint4 wtf[16];
    #pragma unroll
    for (int q = 0; q < 16; ++q) {
        wtf[q] = WTm4[(size_t)(wv * 16 + q) * 64 + lane];
        LAUNDER4(wtf[q]);
    }
    ((unsigned*)sm.dc)[tid] = 0u;
    ((unsigned*)sm.dc)[512 + tid] = 0u;
    if (tid < 128) sm.w2h[tid] = __float2half(W2[tid]);
    sm.sY[tid] = Y[(long)bbase * TN + tid];
    float c0 = 0.f, c1 = 0.f;
    float wihA[4], wihB[4], bsA[4], bsB[4];
    #pragma unroll
    for (int q = 0; q < 4; ++q) {
        wihA[q] = Wih[q * 128 + lane];
        wihB[q] = Wih[q * 128 + 64 + lane];
        bsA[q] = bih[q * 128 + lane] + bhh[q * 128 + lane];
        bsB[q] = bih[q * 128 + 64 + lane] + bhh[q * 128 + 64 + lane];
    }
    const float fcwa = fcW[lane];
    const float fcwb = fcW[64 + lane];
    const float fcw2 = fcW[128], fcb0 = fcb[0];
    __syncthreads();

    #pragma unroll 1
    for (int s = 0; s < TN; ++s) {
        // ==== region A: p + gates MFMAs (rows = g, 8/16 real) ====
        {
            const int m = lane & 15, q = lane >> 4;
            FU a4[4];
            #pragma unroll
            for (int kt = 0; kt < 4; ++kt) {
                int slot = ((kt * 4 + q) & 15) ^ m;      // d-part chunks
                a4[kt].u = *(const uint4*)&sm.dc[m * 256 + slot * 8];
            }
            float4v pacc = (float4v){0.f, 0.f, 0.f, 0.f};
            float4v gacc[4];
            #pragma unroll
            for (int i = 0; i < 4; ++i) gacc[i] = (float4v){0.f, 0.f, 0.f, 0.f};
            #pragma unroll
            for (int kt = 0; kt < 4; ++kt) {
                FU b; b.u = w1f[kt];
                pacc = __builtin_amdgcn_mfma_f32_16x16x32_f16(a4[kt].h8, b.h8, pacc, 0, 0, 0);
            }
            #pragma unroll
            for (int i = 0; i < 4; ++i) {
                #pragma unroll
                for (int kt = 0; kt < 4; ++kt) {
                    FU b; b.u = wtf[i * 4 + kt];
                    gacc[i] = __builtin_amdgcn_mfma_f32_16x16x32_f16(a4[kt].h8, b.h8, gacc[i], 0, 0, 0);
                }
            }
            #pragma unroll
            for (int kt = 0; kt < 4; ++kt) {
                int slot = 16 | (((kt * 4 + q) & 15) ^ m);   // c-part chunks
                FU a; a.u = *(const uint4*)&sm.dc[m * 256 + slot * 8];
                FU b; b.u = w1f[4 + kt];
                pacc = __builtin_amdgcn_mfma_f32_16x16x32_f16(a.h8, b.h8, pacc, 0, 0, 0);
            }
            if (lane < 32) {
                const int row0 = (lane >> 4) * 4, col = lane & 15;
                #pragma unroll
                for (int r = 0; r < 4; ++r)
                    sm.spH[(row0 + r) * 128 + wv * 16 + col] = __float2half(pacc[r]);
                #pragma unroll
                for (int i = 0; i < 4; ++i) {
                    #pragma unroll
                    for (int r = 0; r < 4; ++r)
                        sm.sg[(row0 + r) * 512 + (wv * 4 + i) * 16 + col] = gacc[i][r];
                }
            }
        }
        __syncthreads();   // b1

        // ==== phase 3: wave-local for own g: e -> softmax -> ctx -> y~ -> LSTM ====
        {
            // ph2: ea[t=lane] = sum_f w2[f]*sigma(2x) (inputs pre-scaled by KK).
            // tanh = 2*sigma-1 folded into softmax shift-invariance: arg = 2*ea.
            const uint4* pH = (const uint4*)&sm.spH[g * 128];
            const __half2* w2b = (const __half2*)sm.w2h;
            const __half2 one2 = __float2half2_rn(1.f);
            float ea0 = 0.f, ea1 = 0.f, ea2 = 0.f, ea3 = 0.f;
            #pragma unroll
            for (int u = 0; u < 16; ++u) {
                FU hw; hw.u = hwr[u];
                FU pp; pp.u = pH[u];
                __half2 th0 = sig2(__hadd2(hw.h2[0], pp.h2[0]), one2);
                __half2 th1 = sig2(__hadd2(hw.h2[1], pp.h2[1]), one2);
                __half2 th2 = sig2(__hadd2(hw.h2[2], pp.h2[2]), one2);
                __half2 th3 = sig2(__hadd2(hw.h2[3], pp.h2[3]), one2);
                ea0 = fdot2f(th0, w2b[u * 4 + 0], ea0);
                ea1 = fdot2f(th1, w2b[u * 4 + 1], ea1);
                ea2 = fdot2f(th2, w2b[u * 4 + 2], ea2);
                ea3 = fdot2f(th3, w2b[u * 4 + 3], ea3);
            }
            float ea = (ea0 + ea1) + (ea2 + ea3);
            // ph3: softmax over t (|2ea| bounded ~35, fp32 safe, no max pass)
            float ex = __expf(2.f * ea);
            float ssum = wave_sum64(ex);
            sm.beta[g * 64 + lane] = __float2half(ex * __builtin_amdgcn_rcpf(ssum));
            // ph4: ctx for f=lane and f=lane+64 (same-wave LDS readback of beta)
            const uint4* bb = (const uint4*)&sm.beta[g * 64];
            const uint4* htb = (const uint4*)sm.ht;
            const int ba = ((g << 7) | lane) << 3;
            const int sw7 = lane & 7;
            float ca0 = 0.f, ca1 = 0.f, cb0 = 0.f, cb1 = 0.f;
            #pragma unroll
            for (int u = 0; u < 8; ++u) {
                FU bt; bt.u = bb[u];
                FU h0; h0.u = htb[ba + (u ^ sw7)];
                FU h1; h1.u = htb[ba + 512 + (u ^ sw7)];
                ca0 = fdot2f(h0.h2[0], bt.h2[0], ca0);
                ca1 = fdot2f(h0.h2[1], bt.h2[1], ca1);
                ca0 = fdot2f(h0.h2[2], bt.h2[2], ca0);
                ca1 = fdot2f(h0.h2[3], bt.h2[3], ca1);
                cb0 = fdot2f(h1.h2[0], bt.h2[0], cb0);
                cb1 = fdot2f(h1.h2[1], bt.h2[1], cb1);
                cb0 = fdot2f(h1.h2[2], bt.h2[2], cb0);
                cb1 = fdot2f(h1.h2[3], bt.h2[3], cb1);
            }
            float ctxA = ca0 + ca1, ctxB = cb0 + cb1;
            sm.ctxH[g * 128 + lane] = __float2half(ctxA);
            sm.ctxH[g * 128 + 64 + lane] = __float2half(ctxB);
            // ph5: y~ via DPP wave reduce (covers all 128 f: own + mirror)
            float v = wave_sum64(ctxA * fcwa + ctxB * fcwb);
            float syg = v + fmaf(sm.sY[g * 64 + s], fcw2, fcb0);
            // ph7: LSTM cell for feats lane and lane+64
            float a0A = sm.sg[g * 512 + lane]       + fmaf(syg, wihA[0], bsA[0]);
            float a1A = sm.sg[g * 512 + 128 + lane] + fmaf(syg, wihA[1], bsA[1]);
            float a2A = sm.sg[g * 512 + 256 + lane] + fmaf(syg, wihA[2], bsA[2]);
            float a3A = sm.sg[g * 512 + 384 + lane] + fmaf(syg, wihA[3], bsA[3]);
            float a0B = sm.sg[g * 512 + 64 + lane]  + fmaf(syg, wihB[0], bsB[0]);
            float a1B = sm.sg[g * 512 + 192 + lane] + fmaf(syg, wihB[1], bsB[1]);
            float a2B = sm.sg[g * 512 + 320 + lane] + fmaf(syg, wihB[2], bsB[2]);
            float a3B = sm.sg[g * 512 + 448 + lane] + fmaf(syg, wihB[3], bsB[3]);
            float iA = fast_sigmoid(a0A), fA = fast_sigmoid(a1A);
            float gA = fast_tanhf(a2A),  oA = fast_sigmoid(a3A);
            c0 = fmaf(fA, c0, iA * gA);
            float dA = oA * fast_tanhf(c0);
            float iB = fast_sigmoid(a0B), fB = fast_sigmoid(a1B);
            float gB = fast_tanhf(a2B),  oB = fast_sigmoid(a3B);
            c1 = fmaf(fB, c1, iB * gB);
            float dB = oB * fast_tanhf(c1);
            sm.dc[dc_off(g, lane)] = __float2half(dA);
            sm.dc[dc_off(g, 64 + lane)] = __float2half(dB);
            sm.dc[dc_off(g, 128 + lane)] = __float2half(c0);
            sm.dc[dc_off(g, 192 + lane)] = __float2half(c1);
        }
        __syncthreads();   // b2 (step end)
    }

    // ---- epilogue: all 8 waves, wave-local data ----
    {
        float part = __half2float(sm.dc[dc_off(g, lane)]) * fcfW[lane]
                   + __half2float(sm.dc[dc_off(g, 64 + lane)]) * fcfW[64 + lane]
                   + __half2float(sm.ctxH[g * 128 + lane]) * fcfW[128 + lane]
                   + __half2float(sm.ctxH[g * 128 + 64 + lane]) * fcfW[192 + lane];
        #pragma unroll
        for (int d = 1; d < 64; d <<= 1) part += __shfl_xor(part, d, 64);
        if (lane == 0) out[bbase + g] = part + fcfb[0];
    }
}

extern "C" void kernel_launch(void* const* d_in, const int* in_sizes, int n_in,
                              void* d_out, int out_size, void* d_ws, size_t ws_size,
                              hipStream_t stream) {
    const float* H    = (const float*)d_in[0];
    const float* Y    = (const float*)d_in[1];
    const float* W1   = (const float*)d_in[2];
    const float* b1   = (const float*)d_in[3];
    const float* W2   = (const float*)d_in[4];
    // d_in[5] = attn_b2: softmax-shift-invariant, unused
    const float* Wih  = (const float*)d_in[6];
    const float* Whh  = (const float*)d_in[7];
    const float* bih  = (const float*)d_in[8];
    const float* bhh  = (const float*)d_in[9];
    const float* fcW  = (const float*)d_in[10];
    const float* fcb  = (const float*)d_in[11];
    const float* fcfW = (const float*)d_in[12];
    const float* fcfb = (const float*)d_in[13];

    char* ws = (char*)d_ws;
    __half* HWh = (__half*)ws;                            // 32 MB
    __half* HhT = (__half*)(ws + 33554432);               // 32 MB
    __half* W1m = (__half*)(ws + 2 * 33554432);           // 64 KB
    __half* WTm = (__half*)(ws + 2 * 33554432 + 65536);   // 128 KB
    float* out = (float*)d_out;

    prep_hw<<<BN * TN / 16, 256, 0, stream>>>(H, W1, b1, HWh);
    prep_ht<<<BN, 256, 0, stream>>>(H, HhT);
    prep_w1m<<<128, 256, 0, stream>>>(W1, W1m);
    prep_wtm<<<256, 256, 0, stream>>>(Whh, WTm);
    decoder_scan<<<NBLK, 512, 0, stream>>>(Y, W2, Wih, bih, bhh,
                                           fcW, fcb, fcfW, fcfb,
                                           HWh, HhT, (const uint4*)W1m,
                                           (const uint4*)WTm, out);
}